// Round 1
// 1136.706 us; speedup vs baseline: 1.0230x; 1.0230x over previous
//
#include <hip/hip_runtime.h>
#include <cstdint>
#include <cstddef>

// Int8Linear + exact GELU on MI355X — int8 MFMA, 256x256 8-phase schedule.
// y[m][n] = gelu( scale[n] * sum_k x[m][k]*Wq[n][k] + b[n] )
// M=8192, N=11008, K=4096.
//
// Round 3: port gemm_i8 from the m97 128² 2-barrier structure (22% MfmaUtil)
// to the 256² 8-phase template (T3+T4 counted vmcnt, T2 LDS XOR-swizzle,
// T5 setprio). i8 maps 1:1 onto the bf16 template geometry: BK=128 i8 bytes
// per row (= bf16's 64 elems), identical ds_read/stage counts per phase,
// 2x MACs per MFMA. Stage schedule derived from region free/deadline
// analysis: P1/P2 stage A(2j+1), P3/P4 B(2j+2), P5/P6 A(2j+2), P7/P8
// B(2j+3); vmcnt(4) at P4/P8 only. Tail handled by clamping tile index
// (redundant loads into dead regions keep vmcnt counts uniform).

#define Msz 8192
#define Nsz 11008
#define Ksz 4096

// ---- main-GEMM geometry (256² 8-phase) ----
#define TM 256
#define TN 256
#define TK 128            // K-bytes (= K-elems, i8) per tile row
#define NT (Ksz / TK)     // 32 K-tiles
#define NI (NT / 2)       // 16 iterations (2 tiles per 8-phase iteration)
#define HALF (128 * TK)   // 16384 B: half-tile (128 rows x 128 B)
#define NWG ((Msz / TM) * (Nsz / TN))  // 32*43 = 1376, % 8 == 0
#define CPX (NWG / 8)                  // 172 blocks per XCD chunk

// ---- fallback geometry (unchanged round-1 kernel) ----
#define BM 128
#define BN 128

typedef __attribute__((ext_vector_type(4))) int int4v;
typedef __attribute__((ext_vector_type(8))) short short8;
typedef __attribute__((ext_vector_type(4))) float floatx4;

__device__ __forceinline__ void async16(const void* g, void* l) {
  __builtin_amdgcn_global_load_lds(
      (const __attribute__((address_space(1))) void*)g,
      (__attribute__((address_space(3))) void*)l, 16, 0, 0);
}

// ---- pre-pass 1: per-row symmetric int8 quantization of x -----------------
__global__ __launch_bounds__(256) void quant_x(
    const float* __restrict__ x, signed char* __restrict__ xq,
    float* __restrict__ qs) {
  const int row = blockIdx.x;
  const int tid = threadIdx.x;
  const int lane = tid & 63;
  const int wave = tid >> 6;
  const float4* xr = (const float4*)(x + (size_t)row * Ksz);

  float4 v[4];
  float m = 0.f;
#pragma unroll
  for (int t = 0; t < 4; ++t) {
    v[t] = xr[tid + t * 256];
    m = fmaxf(m, fmaxf(fmaxf(fabsf(v[t].x), fabsf(v[t].y)),
                       fmaxf(fabsf(v[t].z), fabsf(v[t].w))));
  }
#pragma unroll
  for (int o = 32; o > 0; o >>= 1) m = fmaxf(m, __shfl_down(m, o));
  __shared__ float sm[4];
  if (lane == 0) sm[wave] = m;
  __syncthreads();
  const float am = fmaxf(fmaxf(sm[0], sm[1]), fmaxf(sm[2], sm[3]));
  const float rs = am > 0.f ? 127.0f / am : 0.f;
  if (tid == 0) qs[row] = am * (1.0f / 127.0f);

  unsigned* outd = (unsigned*)(xq + (size_t)row * Ksz);
#pragma unroll
  for (int t = 0; t < 4; ++t) {
    int q0 = __float2int_rn(fminf(fmaxf(v[t].x * rs, -127.f), 127.f));
    int q1 = __float2int_rn(fminf(fmaxf(v[t].y * rs, -127.f), 127.f));
    int q2 = __float2int_rn(fminf(fmaxf(v[t].z * rs, -127.f), 127.f));
    int q3 = __float2int_rn(fminf(fmaxf(v[t].w * rs, -127.f), 127.f));
    outd[tid + t * 256] = (unsigned)(q0 & 255) | ((unsigned)(q1 & 255) << 8) |
                          ((unsigned)(q2 & 255) << 16) | ((unsigned)q3 << 24);
  }
}

// ---- pre-pass 2: pack Wq int32 -> int8 ------------------------------------
__global__ __launch_bounds__(256) void pack_w(const int4* __restrict__ w,
                                              unsigned* __restrict__ o) {
  const unsigned gid = blockIdx.x * 256 + threadIdx.x;
  const unsigned stride = 11008u * 256u;
#pragma unroll
  for (int t = 0; t < 4; ++t) {
    const unsigned idx = gid + t * stride;
    const int4 a = w[idx];
    o[idx] = (unsigned)(a.x & 255) | ((unsigned)(a.y & 255) << 8) |
             ((unsigned)(a.z & 255) << 16) | ((unsigned)a.w << 24);
  }
}

// ---- 8-phase GEMM helpers -------------------------------------------------
// Stage one half-tile (128 rows x 128 B = 16 KB) via 2x global_load_lds per
// thread. LDS dest is LINEAR (wave-uniform base + lane*16, required by HW);
// the T2 swizzle is pre-applied to the GLOBAL source column so that
// LDS[r][c] holds global k-slot (c ^ (r&7)). Reads XOR the same way.
__device__ __forceinline__ void stage_half(signed char* dst,
                                           const signed char* src, int grow0,
                                           int kt, int tid) {
  const int c = tid & 7;
  const int k0 = kt * TK;
#pragma unroll
  for (int rho = 0; rho < 2; ++rho) {
    const int rl = rho * 64 + (tid >> 3);
    async16(src + (size_t)(grow0 + rl) * Ksz + k0 + ((c ^ (rl & 7)) << 4),
            dst + rho * 8192 + tid * 16);
  }
}

__device__ __forceinline__ int4v ldfrag(const signed char* s, int row,
                                        int slot) {
  // 16B ds_read_b128 at swizzled slot: 2-way bank aliasing only (free).
  return *(const int4v*)(s + row * TK + (((slot) ^ (row & 7)) << 4));
}

// One phase: {ds_read subtile || issue 1 half-tile stage} -> barrier ->
// lgkmcnt(0) -> setprio(1) 16x MFMA setprio(0) -> [vmcnt(4)] -> barrier.
#define PHASE(b, q, LOADB, SDST, GSRC, GROW0, KT, VM)                        \
  {                                                                          \
    int4v afr[2][2];                                                         \
    _Pragma("unroll") for (int ii = 0; ii < 2; ++ii) {                       \
      const int ar = wr * 128 + ((2 * (q) + ii) << 4) + (lane & 15);         \
      _Pragma("unroll") for (int kk = 0; kk < 2; ++kk)                       \
          afr[ii][kk] = ldfrag(sA[b], ar, kk * 4 + (lane >> 4));             \
    }                                                                        \
    if (LOADB) {                                                             \
      _Pragma("unroll") for (int jj = 0; jj < 4; ++jj) {                     \
        const int br = wc * 64 + (jj << 4) + (lane & 15);                    \
        _Pragma("unroll") for (int kk = 0; kk < 2; ++kk)                     \
            bfr[jj][kk] = ldfrag(sB[b], br, kk * 4 + (lane >> 4));           \
      }                                                                      \
    }                                                                        \
    stage_half(SDST, GSRC, GROW0, KT, tid);                                  \
    if (LOADB) asm volatile("s_waitcnt lgkmcnt(8)" ::: "memory");            \
    __builtin_amdgcn_s_barrier();                                            \
    asm volatile("s_waitcnt lgkmcnt(0)" ::: "memory");                       \
    __builtin_amdgcn_s_setprio(1);                                           \
    _Pragma("unroll") for (int kk = 0; kk < 2; ++kk)                         \
        _Pragma("unroll") for (int ii = 0; ii < 2; ++ii)                     \
            _Pragma("unroll") for (int jj = 0; jj < 4; ++jj)                 \
                acc[2 * (q) + ii][jj] =                                      \
                    __builtin_amdgcn_mfma_i32_16x16x64_i8(                   \
                        afr[ii][kk], bfr[jj][kk], acc[2 * (q) + ii][jj], 0,  \
                        0, 0);                                               \
    __builtin_amdgcn_s_setprio(0);                                           \
    if (VM) asm volatile("s_waitcnt vmcnt(4)" ::: "memory");                 \
    __builtin_amdgcn_s_barrier();                                            \
  }

// ---- main GEMM: 256x256 tile, 8 waves (2M x 4N), 128 KiB LDS dbuf ---------
__global__ __launch_bounds__(512, 2) void gemm_i8(
    const signed char* __restrict__ A8,  // [M][K] int8
    const signed char* __restrict__ B8,  // [N][K] int8
    const float* __restrict__ qs,        // [M] per-row x scales
    const float* __restrict__ scale, const float* __restrict__ bias,
    float* __restrict__ out) {
  __shared__ signed char sA[2][TM * TK];  // 2 x 32 KB
  __shared__ signed char sB[2][TN * TK];  // 2 x 32 KB

  const int tid = threadIdx.x;
  const int wave = tid >> 6;
  const int lane = tid & 63;
  const int wr = wave >> 2;  // 0..1 -> M-half of tile (rows wr*128..+127)
  const int wc = wave & 3;   // 0..3 -> N-quarter (cols wc*64..+63)

  // XCD-chunked bijective swizzle (NWG % 8 == 0), M fastest within chunk:
  // each XCD works ~5.4 consecutive N-panels -> B panel L2-resident.
  const int bid = blockIdx.x;
  const int swz = (bid & 7) * CPX + (bid >> 3);
  const int bm0 = (swz & 31) * TM;  // 32 M-blocks
  const int bn0 = (swz >> 5) * TN;  // 43 N-blocks

  int4v acc[8][4];
#pragma unroll
  for (int i = 0; i < 8; ++i)
#pragma unroll
    for (int j = 0; j < 4; ++j) acc[i][j] = (int4v)0;
  int4v bfr[4][2];  // B frags for current K-tile, live across 4 phases

  // Prologue: tile0 (A+B -> buf0) + tile1 B halves (-> buf1); A(1) comes in
  // P1/P2 of iter 0. vmcnt(4) completes tile0's 8 loads, leaves B(1) 4.
  stage_half(sA[0], A8, bm0, 0, tid);
  stage_half(sA[0] + HALF, A8, bm0 + 128, 0, tid);
  stage_half(sB[0], B8, bn0, 0, tid);
  stage_half(sB[0] + HALF, B8, bn0 + 128, 0, tid);
  stage_half(sB[1], B8, bn0, 1, tid);
  stage_half(sB[1] + HALF, B8, bn0 + 128, 1, tid);
  asm volatile("s_waitcnt vmcnt(4)" ::: "memory");
  __builtin_amdgcn_s_barrier();

  for (int j = 0; j < NI; ++j) {
    const int tA1 = 2 * j + 1;                              // always < NT
    const int tB2 = (2 * j + 2 < NT) ? 2 * j + 2 : NT - 1;  // clamp tail
    const int tB3 = (2 * j + 3 < NT) ? 2 * j + 3 : NT - 1;  // clamp tail
    // phases 1-4: compute tile 2j from buf0
    PHASE(0, 0, true, sA[1], A8, bm0, tA1, false)
    PHASE(0, 1, false, sA[1] + HALF, A8, bm0 + 128, tA1, false)
    PHASE(0, 2, false, sB[0], B8, bn0, tB2, false)
    PHASE(0, 3, false, sB[0] + HALF, B8, bn0 + 128, tB2, true)
    // phases 5-8: compute tile 2j+1 from buf1
    PHASE(1, 0, true, sA[0], A8, bm0, tB2, false)
    PHASE(1, 1, false, sA[0] + HALF, A8, bm0 + 128, tB2, false)
    PHASE(1, 2, false, sB[1], B8, bn0, tB3, false)
    PHASE(1, 3, false, sB[1] + HALF, B8, bn0 + 128, tB3, true)
  }
  // Drain stray (clamped) stages before LDS dealloc / epilogue.
  asm volatile("s_waitcnt vmcnt(0)" ::: "memory");

  // Epilogue. C/D layout: col = lane&15 (N), row = (lane>>4)*4 + reg (M).
  float sc[4], bb[4];
#pragma unroll
  for (int jj = 0; jj < 4; ++jj) {
    const int col = bn0 + wc * 64 + jj * 16 + (lane & 15);
    sc[jj] = scale[col];
    bb[jj] = bias[col];
  }
#pragma unroll
  for (int i = 0; i < 8; ++i) {
    const int row0 = bm0 + wr * 128 + i * 16 + (lane >> 4) * 4;
    float qv[4];
#pragma unroll
    for (int r = 0; r < 4; ++r) qv[r] = qs[row0 + r];
#pragma unroll
    for (int jj = 0; jj < 4; ++jj) {
      const int col = bn0 + wc * 64 + jj * 16 + (lane & 15);
#pragma unroll
      for (int r = 0; r < 4; ++r) {
        float v = (float)acc[i][jj][r] * (qv[r] * sc[jj]) + bb[jj];
        v = 0.5f * v * (1.0f + erff(v * 0.7071067811865476f));
        out[(size_t)(row0 + r) * Nsz + col] = v;
      }
    }
  }
}

// ---- fallback bf16 GEMM (inline conversion) if ws is too small ------------
__device__ __forceinline__ unsigned int f2bf(float f) {
  unsigned int u = __builtin_bit_cast(unsigned int, f);
  unsigned int r = u + 0x7FFFu + ((u >> 16) & 1u);
  return r >> 16;
}

__global__ __launch_bounds__(256) void gemm_bf16_inline(
    const float* __restrict__ Af, const int* __restrict__ Bi,
    const float* __restrict__ scale, const float* __restrict__ bias,
    float* __restrict__ out) {
  __shared__ unsigned short sA[BM * 32];
  __shared__ unsigned short sB[BN * 32];
  const int tid = threadIdx.x;
  const int wave = tid >> 6;
  const int lane = tid & 63;
  const int bn0 = blockIdx.x * BN;
  const int bm0 = blockIdx.y * BM;
  const int mw = (wave >> 1) * 64;
  const int nw = (wave & 1) * 64;
  floatx4 acc[4][4];
#pragma unroll
  for (int i = 0; i < 4; ++i)
#pragma unroll
    for (int j = 0; j < 4; ++j) acc[i][j] = (floatx4)0.f;
  for (int k0 = 0; k0 < Ksz; k0 += 32) {
#pragma unroll
    for (int it = 0; it < 4; ++it) {
      const int f = tid + it * 256;
      const int row = f >> 3;
      const int c4 = (f & 7) * 4;
      const float4 v = *(const float4*)(Af + (size_t)(bm0 + row) * Ksz + k0 + c4);
      uint2 p;
      p.x = f2bf(v.x) | (f2bf(v.y) << 16);
      p.y = f2bf(v.z) | (f2bf(v.w) << 16);
      *(uint2*)&sA[row * 32 + c4] = p;
      const int4 w2 = *(const int4*)(Bi + (size_t)(bn0 + row) * Ksz + k0 + c4);
      uint2 q;
      q.x = f2bf((float)w2.x) | (f2bf((float)w2.y) << 16);
      q.y = f2bf((float)w2.z) | (f2bf((float)w2.w) << 16);
      *(uint2*)&sB[row * 32 + c4] = q;
    }
    __syncthreads();
    short8 af[4], bfr[4];
    const int kof2 = (lane >> 4) * 8;
#pragma unroll
    for (int i = 0; i < 4; ++i) {
      af[i] = *(const short8*)&sA[(mw + i * 16 + (lane & 15)) * 32 + kof2];
      bfr[i] = *(const short8*)&sB[(nw + i * 16 + (lane & 15)) * 32 + kof2];
    }
#pragma unroll
    for (int i = 0; i < 4; ++i)
#pragma unroll
      for (int j = 0; j < 4; ++j)
        acc[i][j] =
            __builtin_amdgcn_mfma_f32_16x16x32_bf16(af[i], bfr[j], acc[i][j], 0, 0, 0);
    __syncthreads();
  }
#pragma unroll
  for (int j = 0; j < 4; ++j) {
    const int col = bn0 + nw + j * 16 + (lane & 15);
    const float s = scale[col];
    const float bb = bias[col];
#pragma unroll
    for (int i = 0; i < 4; ++i) {
      const int row0 = bm0 + mw + i * 16 + (lane >> 4) * 4;
#pragma unroll
      for (int r = 0; r < 4; ++r) {
        float v = acc[i][j][r] * s + bb;
        v = 0.5f * v * (1.0f + erff(v * 0.7071067811865476f));
        out[(size_t)(row0 + r) * Nsz + col] = v;
      }
    }
  }
}

extern "C" void kernel_launch(void* const* d_in, const int* in_sizes, int n_in,
                              void* d_out, int out_size, void* d_ws, size_t ws_size,
                              hipStream_t stream) {
  const float* x = (const float*)d_in[0];      // [M][K] fp32
  const int* Wq = (const int*)d_in[1];         // [N][K] int32 (int8 values)
  const float* scale = (const float*)d_in[2];  // [N]
  const float* bias = (const float*)d_in[3];   // [N]
  float* out = (float*)d_out;                  // [M][N] fp32

  const size_t nx = (size_t)Msz * Ksz;   // 33,554,432
  const size_t nwq = (size_t)Nsz * Ksz;  // 45,088,768
  const size_t need = nx + nwq + Msz * sizeof(float);

  if (ws_size >= need) {
    signed char* xq = (signed char*)d_ws;
    signed char* wp = xq + nx;
    float* qsd = (float*)(wp + nwq);
    quant_x<<<dim3(Msz), dim3(256), 0, stream>>>(x, xq, qsd);
    pack_w<<<dim3((unsigned)(nwq / (16 * 256))), dim3(256), 0, stream>>>(
        (const int4*)Wq, (unsigned*)wp);
    gemm_i8<<<dim3(NWG), dim3(512), 0, stream>>>(xq, wp, qsd, scale, bias, out);
  } else {
    dim3 grid(Nsz / BN, Msz / BM);
    gemm_bf16_inline<<<grid, dim3(256), 0, stream>>>(x, Wq, scale, bias, out);
  }
}

// Round 2
// 1134.087 us; speedup vs baseline: 1.0254x; 1.0023x over previous
//
#include <hip/hip_runtime.h>
#include <cstdint>
#include <cstddef>

// Int8Linear + exact GELU on MI355X — int8 MFMA, 256x256 8-phase schedule.
// y[m][n] = gelu( scale[n] * sum_k x[m][k]*Wq[n][k] + b[n] )
// M=8192, N=11008, K=4096.
//
// Round 4: round-3's 8-phase port was null (MfmaUtil stuck at 22.9%) while
// the identical bf16 template measures 62%. Phase time 2383 cyc vs ~1100
// expected => codegen, not schedule. Fix: (a) sched_barrier(0) pins so the
// ds_read/stage ISSUE cannot be sunk past s_barrier (raw s_barrier builtin
// is not a scheduling fence; rule #18), (b) drop the blunt asm lgkmcnt(0)
// full-drain so the compiler emits counted lgkm waits interleaved with the
// MFMA cluster (kk=0 MFMAs start while kk=1/B reads drain). Correctness:
// every read completes before its MFMA use (compiler-enforced), which
// precedes the barrier that precedes any overwrite of that LDS region.

#define Msz 8192
#define Nsz 11008
#define Ksz 4096

// ---- main-GEMM geometry (256² 8-phase) ----
#define TM 256
#define TN 256
#define TK 128            // K-bytes (= K-elems, i8) per tile row
#define NT (Ksz / TK)     // 32 K-tiles
#define NI (NT / 2)       // 16 iterations (2 tiles per 8-phase iteration)
#define HALF (128 * TK)   // 16384 B: half-tile (128 rows x 128 B)
#define NWG ((Msz / TM) * (Nsz / TN))  // 32*43 = 1376, % 8 == 0
#define CPX (NWG / 8)                  // 172 blocks per XCD chunk

// ---- fallback geometry ----
#define BM 128
#define BN 128

typedef __attribute__((ext_vector_type(4))) int int4v;
typedef __attribute__((ext_vector_type(8))) short short8;
typedef __attribute__((ext_vector_type(4))) float floatx4;

__device__ __forceinline__ void async16(const void* g, void* l) {
  __builtin_amdgcn_global_load_lds(
      (const __attribute__((address_space(1))) void*)g,
      (__attribute__((address_space(3))) void*)l, 16, 0, 0);
}

// ---- pre-pass 1: per-row symmetric int8 quantization of x -----------------
__global__ __launch_bounds__(256) void quant_x(
    const float* __restrict__ x, signed char* __restrict__ xq,
    float* __restrict__ qs) {
  const int row = blockIdx.x;
  const int tid = threadIdx.x;
  const int lane = tid & 63;
  const int wave = tid >> 6;
  const float4* xr = (const float4*)(x + (size_t)row * Ksz);

  float4 v[4];
  float m = 0.f;
#pragma unroll
  for (int t = 0; t < 4; ++t) {
    v[t] = xr[tid + t * 256];
    m = fmaxf(m, fmaxf(fmaxf(fabsf(v[t].x), fabsf(v[t].y)),
                       fmaxf(fabsf(v[t].z), fabsf(v[t].w))));
  }
#pragma unroll
  for (int o = 32; o > 0; o >>= 1) m = fmaxf(m, __shfl_down(m, o));
  __shared__ float sm[4];
  if (lane == 0) sm[wave] = m;
  __syncthreads();
  const float am = fmaxf(fmaxf(sm[0], sm[1]), fmaxf(sm[2], sm[3]));
  const float rs = am > 0.f ? 127.0f / am : 0.f;
  if (tid == 0) qs[row] = am * (1.0f / 127.0f);

  unsigned* outd = (unsigned*)(xq + (size_t)row * Ksz);
#pragma unroll
  for (int t = 0; t < 4; ++t) {
    int q0 = __float2int_rn(fminf(fmaxf(v[t].x * rs, -127.f), 127.f));
    int q1 = __float2int_rn(fminf(fmaxf(v[t].y * rs, -127.f), 127.f));
    int q2 = __float2int_rn(fminf(fmaxf(v[t].z * rs, -127.f), 127.f));
    int q3 = __float2int_rn(fminf(fmaxf(v[t].w * rs, -127.f), 127.f));
    outd[tid + t * 256] = (unsigned)(q0 & 255) | ((unsigned)(q1 & 255) << 8) |
                          ((unsigned)(q2 & 255) << 16) | ((unsigned)q3 << 24);
  }
}

// ---- pre-pass 2: pack Wq int32 -> int8 ------------------------------------
__global__ __launch_bounds__(256) void pack_w(const int4* __restrict__ w,
                                              unsigned* __restrict__ o) {
  const unsigned gid = blockIdx.x * 256 + threadIdx.x;
  const unsigned stride = 11008u * 256u;
#pragma unroll
  for (int t = 0; t < 4; ++t) {
    const unsigned idx = gid + t * stride;
    const int4 a = w[idx];
    o[idx] = (unsigned)(a.x & 255) | ((unsigned)(a.y & 255) << 8) |
             ((unsigned)(a.z & 255) << 16) | ((unsigned)a.w << 24);
  }
}

// ---- 8-phase GEMM helpers -------------------------------------------------
// Stage one half-tile (128 rows x 128 B = 16 KB) via 2x global_load_lds per
// thread. LDS dest is LINEAR (wave-uniform base + lane*16, required by HW);
// the T2 swizzle is pre-applied to the GLOBAL source column so that
// LDS[r][c] holds global k-slot (c ^ (r&7)). Reads XOR the same way.
__device__ __forceinline__ void stage_half(signed char* dst,
                                           const signed char* src, int grow0,
                                           int kt, int tid) {
  const int c = tid & 7;
  const int k0 = kt * TK;
#pragma unroll
  for (int rho = 0; rho < 2; ++rho) {
    const int rl = rho * 64 + (tid >> 3);
    async16(src + (size_t)(grow0 + rl) * Ksz + k0 + ((c ^ (rl & 7)) << 4),
            dst + rho * 8192 + tid * 16);
  }
}

__device__ __forceinline__ int4v ldfrag(const signed char* s, int row,
                                        int slot) {
  // 16B ds_read_b128 at swizzled slot: measured conflict-free.
  return *(const int4v*)(s + row * TK + (((slot) ^ (row & 7)) << 4));
}

// One phase: {ds_read subtile || issue 1 half-tile stage} -> [pin] barrier
// [pin] -> setprio(1) 16x MFMA (compiler-counted lgkm waits) setprio(0) ->
// [vmcnt(4)] -> barrier.
#define PHASE(b, q, LOADB, SDST, GSRC, GROW0, KT, VM)                        \
  {                                                                          \
    int4v afr[2][2];                                                         \
    _Pragma("unroll") for (int ii = 0; ii < 2; ++ii) {                       \
      const int ar = wr * 128 + ((2 * (q) + ii) << 4) + (lane & 15);         \
      _Pragma("unroll") for (int kk = 0; kk < 2; ++kk)                       \
          afr[ii][kk] = ldfrag(sA[b], ar, kk * 4 + (lane >> 4));             \
    }                                                                        \
    if (LOADB) {                                                             \
      _Pragma("unroll") for (int jj = 0; jj < 4; ++jj) {                     \
        const int br = wc * 64 + (jj << 4) + (lane & 15);                    \
        _Pragma("unroll") for (int kk = 0; kk < 2; ++kk)                     \
            bfr[jj][kk] = ldfrag(sB[b], br, kk * 4 + (lane >> 4));           \
      }                                                                      \
    }                                                                        \
    stage_half(SDST, GSRC, GROW0, KT, tid);                                  \
    __builtin_amdgcn_sched_barrier(0); /* reads+stage ISSUED before bar */   \
    __builtin_amdgcn_s_barrier();                                            \
    __builtin_amdgcn_sched_barrier(0); /* MFMA cluster stays after bar */    \
    __builtin_amdgcn_s_setprio(1);                                           \
    _Pragma("unroll") for (int kk = 0; kk < 2; ++kk)                         \
        _Pragma("unroll") for (int ii = 0; ii < 2; ++ii)                     \
            _Pragma("unroll") for (int jj = 0; jj < 4; ++jj)                 \
                acc[2 * (q) + ii][jj] =                                      \
                    __builtin_amdgcn_mfma_i32_16x16x64_i8(                   \
                        afr[ii][kk], bfr[jj][kk], acc[2 * (q) + ii][jj], 0,  \
                        0, 0);                                               \
    __builtin_amdgcn_s_setprio(0);                                           \
    __builtin_amdgcn_sched_barrier(0);                                       \
    if (VM) asm volatile("s_waitcnt vmcnt(4)" ::: "memory");                 \
    __builtin_amdgcn_s_barrier();                                            \
  }

// ---- main GEMM: 256x256 tile, 8 waves (2M x 4N), 128 KiB LDS dbuf ---------
__global__ __launch_bounds__(512, 2) void gemm_i8(
    const signed char* __restrict__ A8,  // [M][K] int8
    const signed char* __restrict__ B8,  // [N][K] int8
    const float* __restrict__ qs,        // [M] per-row x scales
    const float* __restrict__ scale, const float* __restrict__ bias,
    float* __restrict__ out) {
  __shared__ signed char sA[2][TM * TK];  // 2 x 32 KB
  __shared__ signed char sB[2][TN * TK];  // 2 x 32 KB

  const int tid = threadIdx.x;
  const int wave = tid >> 6;
  const int lane = tid & 63;
  const int wr = wave >> 2;  // 0..1 -> M-half of tile
  const int wc = wave & 3;   // 0..3 -> N-quarter

  // XCD-chunked bijective swizzle (NWG % 8 == 0), M fastest within chunk.
  const int bid = blockIdx.x;
  const int swz = (bid & 7) * CPX + (bid >> 3);
  const int bm0 = (swz & 31) * TM;  // 32 M-blocks
  const int bn0 = (swz >> 5) * TN;  // 43 N-blocks

  int4v acc[8][4];
#pragma unroll
  for (int i = 0; i < 8; ++i)
#pragma unroll
    for (int j = 0; j < 4; ++j) acc[i][j] = (int4v)0;
  int4v bfr[4][2];  // B frags for current K-tile, live across 4 phases

  // Prologue: tile0 (A+B -> buf0) + tile1 B halves (-> buf1); A(1) comes in
  // P1/P2 of iter 0. vmcnt(4) completes tile0's 8 loads, leaves B(1)'s 4.
  stage_half(sA[0], A8, bm0, 0, tid);
  stage_half(sA[0] + HALF, A8, bm0 + 128, 0, tid);
  stage_half(sB[0], B8, bn0, 0, tid);
  stage_half(sB[0] + HALF, B8, bn0 + 128, 0, tid);
  stage_half(sB[1], B8, bn0, 1, tid);
  stage_half(sB[1] + HALF, B8, bn0 + 128, 1, tid);
  asm volatile("s_waitcnt vmcnt(4)" ::: "memory");
  __builtin_amdgcn_s_barrier();

  for (int j = 0; j < NI; ++j) {
    const int tA1 = 2 * j + 1;                              // always < NT
    const int tB2 = (2 * j + 2 < NT) ? 2 * j + 2 : NT - 1;  // clamp tail
    const int tB3 = (2 * j + 3 < NT) ? 2 * j + 3 : NT - 1;  // clamp tail
    // phases 1-4: compute tile 2j from buf0
    PHASE(0, 0, true, sA[1], A8, bm0, tA1, false)
    PHASE(0, 1, false, sA[1] + HALF, A8, bm0 + 128, tA1, false)
    PHASE(0, 2, false, sB[0], B8, bn0, tB2, false)
    PHASE(0, 3, false, sB[0] + HALF, B8, bn0 + 128, tB2, true)
    // phases 5-8: compute tile 2j+1 from buf1
    PHASE(1, 0, true, sA[0], A8, bm0, tB2, false)
    PHASE(1, 1, false, sA[0] + HALF, A8, bm0 + 128, tB2, false)
    PHASE(1, 2, false, sB[1], B8, bn0, tB3, false)
    PHASE(1, 3, false, sB[1] + HALF, B8, bn0 + 128, tB3, true)
  }
  // Drain stray (clamped) stages before LDS dealloc / epilogue.
  asm volatile("s_waitcnt vmcnt(0)" ::: "memory");

  // Epilogue. C/D layout: col = lane&15 (N), row = (lane>>4)*4 + reg (M).
  float sc[4], bb[4];
#pragma unroll
  for (int jj = 0; jj < 4; ++jj) {
    const int col = bn0 + wc * 64 + jj * 16 + (lane & 15);
    sc[jj] = scale[col];
    bb[jj] = bias[col];
  }
#pragma unroll
  for (int i = 0; i < 8; ++i) {
    const int row0 = bm0 + wr * 128 + i * 16 + (lane >> 4) * 4;
    float qv[4];
#pragma unroll
    for (int r = 0; r < 4; ++r) qv[r] = qs[row0 + r];
#pragma unroll
    for (int jj = 0; jj < 4; ++jj) {
      const int col = bn0 + wc * 64 + jj * 16 + (lane & 15);
#pragma unroll
      for (int r = 0; r < 4; ++r) {
        float v = (float)acc[i][jj][r] * (qv[r] * sc[jj]) + bb[jj];
        v = 0.5f * v * (1.0f + erff(v * 0.7071067811865476f));
        out[(size_t)(row0 + r) * Nsz + col] = v;
      }
    }
  }
}

// ---- fallback bf16 GEMM (inline conversion) if ws is too small ------------
__device__ __forceinline__ unsigned int f2bf(float f) {
  unsigned int u = __builtin_bit_cast(unsigned int, f);
  unsigned int r = u + 0x7FFFu + ((u >> 16) & 1u);
  return r >> 16;
}

__global__ __launch_bounds__(256) void gemm_bf16_inline(
    const float* __restrict__ Af, const int* __restrict__ Bi,
    const float* __restrict__ scale, const float* __restrict__ bias,
    float* __restrict__ out) {
  __shared__ unsigned short sA[BM * 32];
  __shared__ unsigned short sB[BN * 32];
  const int tid = threadIdx.x;
  const int wave = tid >> 6;
  const int lane = tid & 63;
  const int bn0 = blockIdx.x * BN;
  const int bm0 = blockIdx.y * BM;
  const int mw = (wave >> 1) * 64;
  const int nw = (wave & 1) * 64;
  floatx4 acc[4][4];
#pragma unroll
  for (int i = 0; i < 4; ++i)
#pragma unroll
    for (int j = 0; j < 4; ++j) acc[i][j] = (floatx4)0.f;
  for (int k0 = 0; k0 < Ksz; k0 += 32) {
#pragma unroll
    for (int it = 0; it < 4; ++it) {
      const int f = tid + it * 256;
      const int row = f >> 3;
      const int c4 = (f & 7) * 4;
      const float4 v = *(const float4*)(Af + (size_t)(bm0 + row) * Ksz + k0 + c4);
      uint2 p;
      p.x = f2bf(v.x) | (f2bf(v.y) << 16);
      p.y = f2bf(v.z) | (f2bf(v.w) << 16);
      *(uint2*)&sA[row * 32 + c4] = p;
      const int4 w2 = *(const int4*)(Bi + (size_t)(bn0 + row) * Ksz + k0 + c4);
      uint2 q;
      q.x = f2bf((float)w2.x) | (f2bf((float)w2.y) << 16);
      q.y = f2bf((float)w2.z) | (f2bf((float)w2.w) << 16);
      *(uint2*)&sB[row * 32 + c4] = q;
    }
    __syncthreads();
    short8 af[4], bfr[4];
    const int kof2 = (lane >> 4) * 8;
#pragma unroll
    for (int i = 0; i < 4; ++i) {
      af[i] = *(const short8*)&sA[(mw + i * 16 + (lane & 15)) * 32 + kof2];
      bfr[i] = *(const short8*)&sB[(nw + i * 16 + (lane & 15)) * 32 + kof2];
    }
#pragma unroll
    for (int i = 0; i < 4; ++i)
#pragma unroll
      for (int j = 0; j < 4; ++j)
        acc[i][j] =
            __builtin_amdgcn_mfma_f32_16x16x32_bf16(af[i], bfr[j], acc[i][j], 0, 0, 0);
    __syncthreads();
  }
#pragma unroll
  for (int j = 0; j < 4; ++j) {
    const int col = bn0 + nw + j * 16 + (lane & 15);
    const float s = scale[col];
    const float bb = bias[col];
#pragma unroll
    for (int i = 0; i < 4; ++i) {
      const int row0 = bm0 + mw + i * 16 + (lane >> 4) * 4;
#pragma unroll
      for (int r = 0; r < 4; ++r) {
        float v = acc[i][j][r] * s + bb;
        v = 0.5f * v * (1.0f + erff(v * 0.7071067811865476f));
        out[(size_t)(row0 + r) * Nsz + col] = v;
      }
    }
  }
}

extern "C" void kernel_launch(void* const* d_in, const int* in_sizes, int n_in,
                              void* d_out, int out_size, void* d_ws, size_t ws_size,
                              hipStream_t stream) {
  const float* x = (const float*)d_in[0];      // [M][K] fp32
  const int* Wq = (const int*)d_in[1];         // [N][K] int32 (int8 values)
  const float* scale = (const float*)d_in[2];  // [N]
  const float* bias = (const float*)d_in[3];   // [N]
  float* out = (float*)d_out;                  // [M][N] fp32

  const size_t nx = (size_t)Msz * Ksz;   // 33,554,432
  const size_t nwq = (size_t)Nsz * Ksz;  // 45,088,768
  const size_t need = nx + nwq + Msz * sizeof(float);

  if (ws_size >= need) {
    signed char* xq = (signed char*)d_ws;
    signed char* wp = xq + nx;
    float* qsd = (float*)(wp + nwq);
    quant_x<<<dim3(Msz), dim3(256), 0, stream>>>(x, xq, qsd);
    pack_w<<<dim3((unsigned)(nwq / (16 * 256))), dim3(256), 0, stream>>>(
        (const int4*)Wq, (unsigned*)wp);
    gemm_i8<<<dim3(NWG), dim3(512), 0, stream>>>(xq, wp, qsd, scale, bias, out);
  } else {
    dim3 grid(Nsz / BN, Msz / BM);
    gemm_bf16_inline<<<grid, dim3(256), 0, stream>>>(x, Wq, scale, bias, out);
  }
}

// Round 3
// 1083.571 us; speedup vs baseline: 1.0732x; 1.0466x over previous
//
#include <hip/hip_runtime.h>
#include <cstdint>
#include <cstddef>

// Int8Linear + exact GELU on MI355X — int8 MFMA, 256x256 8-phase schedule,
// deep-prefetch edition.
// y[m][n] = gelu( scale[n] * sum_k x[m][k]*Wq[n][k] + b[n] )
// M=8192, N=11008, K=4096.
//
// Round 5: rounds 3-4 proved the 8-phase structure is schedule-insensitive
// (pins changed nothing; MfmaUtil pinned at 22.9%). Little's-law analysis of
// rounds 0-2 shows the limiter is PREFETCH DEPTH: vmcnt waits sat only 2-3
// phases after issue, so the loop self-paces at phase ~ L_loaded/2.
// Fix: in-place A-slice ring (phase q frees A rows [32q,+32)+[128+32q,+32))
// + B ping-pong (B freed after its P1/P5 register load). Every staged load
// is now issued 6-7 phases before consumption; per-phase derived vmcnts
// (12/14/9) each target a load >=5.4 phases old. LDS stays 128 KiB.

#define Msz 8192
#define Nsz 11008
#define Ksz 4096

// ---- main-GEMM geometry (256² 8-phase) ----
#define TM 256
#define TN 256
#define TK 128            // K-bytes (= K-elems, i8) per tile row
#define NT (Ksz / TK)     // 32 K-tiles
#define NI (NT / 2)       // 16 iterations (2 tiles per 8-phase iteration)
#define HALF (128 * TK)   // 16384 B
#define NWG ((Msz / TM) * (Nsz / TN))  // 32*43 = 1376, % 8 == 0
#define CPX (NWG / 8)                  // 172 blocks per XCD chunk

// ---- fallback geometry ----
#define BM 128
#define BN 128

typedef __attribute__((ext_vector_type(4))) int int4v;
typedef __attribute__((ext_vector_type(8))) short short8;
typedef __attribute__((ext_vector_type(4))) float floatx4;

__device__ __forceinline__ void async16(const void* g, void* l) {
  __builtin_amdgcn_global_load_lds(
      (const __attribute__((address_space(1))) void*)g,
      (__attribute__((address_space(3))) void*)l, 16, 0, 0);
}

// ---- pre-pass 1: per-row symmetric int8 quantization of x -----------------
__global__ __launch_bounds__(256) void quant_x(
    const float* __restrict__ x, signed char* __restrict__ xq,
    float* __restrict__ qs) {
  const int row = blockIdx.x;
  const int tid = threadIdx.x;
  const int lane = tid & 63;
  const int wave = tid >> 6;
  const float4* xr = (const float4*)(x + (size_t)row * Ksz);

  float4 v[4];
  float m = 0.f;
#pragma unroll
  for (int t = 0; t < 4; ++t) {
    v[t] = xr[tid + t * 256];
    m = fmaxf(m, fmaxf(fmaxf(fabsf(v[t].x), fabsf(v[t].y)),
                       fmaxf(fabsf(v[t].z), fabsf(v[t].w))));
  }
#pragma unroll
  for (int o = 32; o > 0; o >>= 1) m = fmaxf(m, __shfl_down(m, o));
  __shared__ float sm[4];
  if (lane == 0) sm[wave] = m;
  __syncthreads();
  const float am = fmaxf(fmaxf(sm[0], sm[1]), fmaxf(sm[2], sm[3]));
  const float rs = am > 0.f ? 127.0f / am : 0.f;
  if (tid == 0) qs[row] = am * (1.0f / 127.0f);

  unsigned* outd = (unsigned*)(xq + (size_t)row * Ksz);
#pragma unroll
  for (int t = 0; t < 4; ++t) {
    int q0 = __float2int_rn(fminf(fmaxf(v[t].x * rs, -127.f), 127.f));
    int q1 = __float2int_rn(fminf(fmaxf(v[t].y * rs, -127.f), 127.f));
    int q2 = __float2int_rn(fminf(fmaxf(v[t].z * rs, -127.f), 127.f));
    int q3 = __float2int_rn(fminf(fmaxf(v[t].w * rs, -127.f), 127.f));
    outd[tid + t * 256] = (unsigned)(q0 & 255) | ((unsigned)(q1 & 255) << 8) |
                          ((unsigned)(q2 & 255) << 16) | ((unsigned)q3 << 24);
  }
}

// ---- pre-pass 2: pack Wq int32 -> int8 ------------------------------------
__global__ __launch_bounds__(256) void pack_w(const int4* __restrict__ w,
                                              unsigned* __restrict__ o) {
  const unsigned gid = blockIdx.x * 256 + threadIdx.x;
  const unsigned stride = 11008u * 256u;
#pragma unroll
  for (int t = 0; t < 4; ++t) {
    const unsigned idx = gid + t * stride;
    const int4 a = w[idx];
    o[idx] = (unsigned)(a.x & 255) | ((unsigned)(a.y & 255) << 8) |
             ((unsigned)(a.z & 255) << 16) | ((unsigned)a.w << 24);
  }
}

// ---- staging helpers ------------------------------------------------------
// B half-tile (128 rows x 128 B = 16 KB), 2 loads/thread. LDS dest LINEAR;
// T2 swizzle pre-applied to the GLOBAL source column (LDS[r][c] holds global
// k-slot c ^ (r&7)); reads XOR the same way.
__device__ __forceinline__ void stage_half(signed char* dst,
                                           const signed char* src, int grow0,
                                           int kt, int tid) {
  const int c = tid & 7;
  const int k0 = kt * TK;
#pragma unroll
  for (int rho = 0; rho < 2; ++rho) {
    const int rl = rho * 64 + (tid >> 3);
    async16(src + (size_t)(grow0 + rl) * Ksz + k0 + ((c ^ (rl & 7)) << 4),
            dst + rho * 8192 + tid * 16);
  }
}

// A slice q: 64 rows = [32q,32q+32) u [128+32q,128+32q+32) = 8 KB,
// 1 load/thread. Same source-side swizzle (row&7 == s&7).
__device__ __forceinline__ void stage_Aslice(signed char* dst,
                                             const signed char* src, int grow0,
                                             int kt, int q, int tid) {
  const int half = tid >> 8;       // 0 -> rows base 0, 1 -> rows base 128
  const int s = (tid & 255) >> 3;  // 0..31 row within slice-half
  const int c = tid & 7;
  const int row = half * 128 + q * 32 + s;
  async16(src + (size_t)(grow0 + row) * Ksz + kt * TK + ((c ^ (s & 7)) << 4),
          dst + half * 16384 + q * 4096 + (tid & 255) * 16);
}

__device__ __forceinline__ int4v ldfrag(const signed char* s, int row,
                                        int slot) {
  // 16B ds_read_b128 at swizzled slot: measured conflict-free (round 1).
  return *(const int4v*)(s + row * TK + (((slot) ^ (row & 7)) << 4));
}

#define VMW(N) asm volatile("s_waitcnt vmcnt(" #N ")" ::: "memory")

// One phase: {ds_read subtile || issue stages} -> [pin] barrier [pin] ->
// setprio(1) 16x MFMA setprio(0) -> [counted vmcnt] -> barrier.
#define PHASE(pA, pB, q, LOADB, STAGE_CODE, WAIT_CODE)                       \
  {                                                                          \
    int4v afr[2][2];                                                         \
    _Pragma("unroll") for (int ii = 0; ii < 2; ++ii) {                       \
      const int ar = wr * 128 + ((2 * (q) + ii) << 4) + (lane & 15);         \
      _Pragma("unroll") for (int kk = 0; kk < 2; ++kk)                       \
          afr[ii][kk] = ldfrag(pA, ar, kk * 4 + (lane >> 4));                \
    }                                                                        \
    if (LOADB) {                                                             \
      _Pragma("unroll") for (int jj = 0; jj < 4; ++jj) {                     \
        const int br = wc * 64 + (jj << 4) + (lane & 15);                    \
        _Pragma("unroll") for (int kk = 0; kk < 2; ++kk)                     \
            bfr[jj][kk] = ldfrag(pB, br, kk * 4 + (lane >> 4));              \
      }                                                                      \
    }                                                                        \
    STAGE_CODE                                                               \
    __builtin_amdgcn_sched_barrier(0);                                       \
    __builtin_amdgcn_s_barrier();                                            \
    __builtin_amdgcn_sched_barrier(0);                                       \
    __builtin_amdgcn_s_setprio(1);                                           \
    _Pragma("unroll") for (int kk = 0; kk < 2; ++kk)                         \
        _Pragma("unroll") for (int ii = 0; ii < 2; ++ii)                     \
            _Pragma("unroll") for (int jj = 0; jj < 4; ++jj)                 \
                acc[2 * (q) + ii][jj] =                                      \
                    __builtin_amdgcn_mfma_i32_16x16x64_i8(                   \
                        afr[ii][kk], bfr[jj][kk], acc[2 * (q) + ii][jj], 0,  \
                        0, 0);                                               \
    __builtin_amdgcn_s_setprio(0);                                           \
    __builtin_amdgcn_sched_barrier(0);                                       \
    WAIT_CODE;                                                               \
    __builtin_amdgcn_s_barrier();                                            \
  }

// ---- main GEMM: 256x256 tile, 8 waves, in-place A-ring + B ping-pong ------
// Stage schedule (iter j, t0=2j, t1=2j+1, t2/t3 clamped):
//   P1: A(t1)s3          P5: A(t2)s3
//   P2: A(t2)s0, B(t2)h0 P6: A(t3)s0, B(t3)h0
//   P3: A(t2)s1, B(t2)h1 P7: A(t3)s1, B(t3)h1
//   P4: A(t2)s2          P8: A(t3)s2
// Every stage lands in rows whose last read is >=1 barrier in the past.
// Derived waits (end of phase): P2:12 P3:14 P4:9 P5:12 P6:12 P7:14 P8:9 —
// each forces a load >=5.4 phases old; never drains below 9 in-loop.
__global__ __launch_bounds__(512, 2) void gemm_i8(
    const signed char* __restrict__ A8,  // [M][K] int8
    const signed char* __restrict__ B8,  // [N][K] int8
    const float* __restrict__ qs,        // [M] per-row x scales
    const float* __restrict__ scale, const float* __restrict__ bias,
    float* __restrict__ out) {
  __shared__ signed char sAbuf[2][TM * TK];  // 2 x 32 KB (A tiles, ring)
  __shared__ signed char sBbuf[2][TN * TK];  // 2 x 32 KB (B ping-pong)
  signed char* sA0 = sAbuf[0];
  signed char* sA1 = sAbuf[1];
  signed char* sB0 = sBbuf[0];
  signed char* sB1 = sBbuf[1];

  const int tid = threadIdx.x;
  const int wave = tid >> 6;
  const int lane = tid & 63;
  const int wr = wave >> 2;  // 0..1 -> M-half of tile
  const int wc = wave & 3;   // 0..3 -> N-quarter

  // XCD-chunked bijective swizzle (NWG % 8 == 0), M fastest within chunk.
  const int bid = blockIdx.x;
  const int swz = (bid & 7) * CPX + (bid >> 3);
  const int bm0 = (swz & 31) * TM;  // 32 M-blocks
  const int bn0 = (swz >> 5) * TN;  // 43 N-blocks

  int4v acc[8][4];
#pragma unroll
  for (int i = 0; i < 8; ++i)
#pragma unroll
    for (int j = 0; j < 4; ++j) acc[i][j] = (int4v)0;
  int4v bfr[4][2];  // B frags for current K-tile, live across 4 phases

  // Prologue: issue in steady-state-mimicking order (15 loads/thread):
  // A0s0, B0h0, A0s1, B0h1, A0s2, A0s3, A1s0, B1h0, A1s1, B1h1, A1s2.
  // vmcnt(9) forces A0{s0,s1}+B0 (P1's needs), leaves 9 in flight.
  stage_Aslice(sA0, A8, bm0, 0, 0, tid);
  stage_half(sB0, B8, bn0, 0, tid);
  stage_Aslice(sA0, A8, bm0, 0, 1, tid);
  stage_half(sB0 + HALF, B8, bn0 + 128, 0, tid);
  stage_Aslice(sA0, A8, bm0, 0, 2, tid);
  stage_Aslice(sA0, A8, bm0, 0, 3, tid);
  stage_Aslice(sA1, A8, bm0, 1, 0, tid);
  stage_half(sB1, B8, bn0, 1, tid);
  stage_Aslice(sA1, A8, bm0, 1, 1, tid);
  stage_half(sB1 + HALF, B8, bn0 + 128, 1, tid);
  stage_Aslice(sA1, A8, bm0, 1, 2, tid);
  VMW(9);
  __builtin_amdgcn_s_barrier();

  for (int j = 0; j < NI; ++j) {
    const int t1 = 2 * j + 1;                               // always < NT
    const int t2 = (2 * j + 2 < NT) ? 2 * j + 2 : NT - 1;   // clamp tail
    const int t3 = (2 * j + 3 < NT) ? 2 * j + 3 : NT - 1;   // clamp tail
    // phases 1-4: compute tile t0 from sA0/sB0
    PHASE(sA0, sB0, 0, true,
          { stage_Aslice(sA1, A8, bm0, t1, 3, tid); }, {})
    PHASE(sA0, sB0, 1, false,
          { stage_Aslice(sA0, A8, bm0, t2, 0, tid);
            stage_half(sB0, B8, bn0, t2, tid); },
          VMW(12))
    PHASE(sA0, sB0, 2, false,
          { stage_Aslice(sA0, A8, bm0, t2, 1, tid);
            stage_half(sB0 + HALF, B8, bn0 + 128, t2, tid); },
          VMW(14))
    PHASE(sA0, sB0, 3, false,
          { stage_Aslice(sA0, A8, bm0, t2, 2, tid); }, VMW(9))
    // phases 5-8: compute tile t1 from sA1/sB1
    PHASE(sA1, sB1, 0, true,
          { stage_Aslice(sA0, A8, bm0, t2, 3, tid); }, VMW(12))
    PHASE(sA1, sB1, 1, false,
          { stage_Aslice(sA1, A8, bm0, t3, 0, tid);
            stage_half(sB1, B8, bn0, t3, tid); },
          VMW(12))
    PHASE(sA1, sB1, 2, false,
          { stage_Aslice(sA1, A8, bm0, t3, 1, tid);
            stage_half(sB1 + HALF, B8, bn0 + 128, t3, tid); },
          VMW(14))
    PHASE(sA1, sB1, 3, false,
          { stage_Aslice(sA1, A8, bm0, t3, 2, tid); }, VMW(9))
  }
  // Drain stray (clamped/tail) stages before epilogue.
  asm volatile("s_waitcnt vmcnt(0)" ::: "memory");

  // Epilogue. C/D layout: col = lane&15 (N), row = (lane>>4)*4 + reg (M).
  float sc[4], bb[4];
#pragma unroll
  for (int jj = 0; jj < 4; ++jj) {
    const int col = bn0 + wc * 64 + jj * 16 + (lane & 15);
    sc[jj] = scale[col];
    bb[jj] = bias[col];
  }
#pragma unroll
  for (int i = 0; i < 8; ++i) {
    const int row0 = bm0 + wr * 128 + i * 16 + (lane >> 4) * 4;
    float qv[4];
#pragma unroll
    for (int r = 0; r < 4; ++r) qv[r] = qs[row0 + r];
#pragma unroll
    for (int jj = 0; jj < 4; ++jj) {
      const int col = bn0 + wc * 64 + jj * 16 + (lane & 15);
#pragma unroll
      for (int r = 0; r < 4; ++r) {
        float v = (float)acc[i][jj][r] * (qv[r] * sc[jj]) + bb[jj];
        v = 0.5f * v * (1.0f + erff(v * 0.7071067811865476f));
        out[(size_t)(row0 + r) * Nsz + col] = v;
      }
    }
  }
}

// ---- fallback bf16 GEMM (inline conversion) if ws is too small ------------
__device__ __forceinline__ unsigned int f2bf(float f) {
  unsigned int u = __builtin_bit_cast(unsigned int, f);
  unsigned int r = u + 0x7FFFu + ((u >> 16) & 1u);
  return r >> 16;
}

__global__ __launch_bounds__(256) void gemm_bf16_inline(
    const float* __restrict__ Af, const int* __restrict__ Bi,
    const float* __restrict__ scale, const float* __restrict__ bias,
    float* __restrict__ out) {
  __shared__ unsigned short sA[BM * 32];
  __shared__ unsigned short sB[BN * 32];
  const int tid = threadIdx.x;
  const int wave = tid >> 6;
  const int lane = tid & 63;
  const int bn0 = blockIdx.x * BN;
  const int bm0 = blockIdx.y * BM;
  const int mw = (wave >> 1) * 64;
  const int nw = (wave & 1) * 64;
  floatx4 acc[4][4];
#pragma unroll
  for (int i = 0; i < 4; ++i)
#pragma unroll
    for (int j = 0; j < 4; ++j) acc[i][j] = (floatx4)0.f;
  for (int k0 = 0; k0 < Ksz; k0 += 32) {
#pragma unroll
    for (int it = 0; it < 4; ++it) {
      const int f = tid + it * 256;
      const int row = f >> 3;
      const int c4 = (f & 7) * 4;
      const float4 v = *(const float4*)(Af + (size_t)(bm0 + row) * Ksz + k0 + c4);
      uint2 p;
      p.x = f2bf(v.x) | (f2bf(v.y) << 16);
      p.y = f2bf(v.z) | (f2bf(v.w) << 16);
      *(uint2*)&sA[row * 32 + c4] = p;
      const int4 w2 = *(const int4*)(Bi + (size_t)(bn0 + row) * Ksz + k0 + c4);
      uint2 q;
      q.x = f2bf((float)w2.x) | (f2bf((float)w2.y) << 16);
      q.y = f2bf((float)w2.z) | (f2bf((float)w2.w) << 16);
      *(uint2*)&sB[row * 32 + c4] = q;
    }
    __syncthreads();
    short8 af[4], bfr[4];
    const int kof2 = (lane >> 4) * 8;
#pragma unroll
    for (int i = 0; i < 4; ++i) {
      af[i] = *(const short8*)&sA[(mw + i * 16 + (lane & 15)) * 32 + kof2];
      bfr[i] = *(const short8*)&sB[(nw + i * 16 + (lane & 15)) * 32 + kof2];
    }
#pragma unroll
    for (int i = 0; i < 4; ++i)
#pragma unroll
      for (int j = 0; j < 4; ++j)
        acc[i][j] =
            __builtin_amdgcn_mfma_f32_16x16x32_bf16(af[i], bfr[j], acc[i][j], 0, 0, 0);
    __syncthreads();
  }
#pragma unroll
  for (int j = 0; j < 4; ++j) {
    const int col = bn0 + nw + j * 16 + (lane & 15);
    const float s = scale[col];
    const float bb = bias[col];
#pragma unroll
    for (int i = 0; i < 4; ++i) {
      const int row0 = bm0 + mw + i * 16 + (lane >> 4) * 4;
#pragma unroll
      for (int r = 0; r < 4; ++r) {
        float v = acc[i][j][r] * s + bb;
        v = 0.5f * v * (1.0f + erff(v * 0.7071067811865476f));
        out[(size_t)(row0 + r) * Nsz + col] = v;
      }
    }
  }
}

extern "C" void kernel_launch(void* const* d_in, const int* in_sizes, int n_in,
                              void* d_out, int out_size, void* d_ws, size_t ws_size,
                              hipStream_t stream) {
  const float* x = (const float*)d_in[0];      // [M][K] fp32
  const int* Wq = (const int*)d_in[1];         // [N][K] int32 (int8 values)
  const float* scale = (const float*)d_in[2];  // [N]
  const float* bias = (const float*)d_in[3];   // [N]
  float* out = (float*)d_out;                  // [M][N] fp32

  const size_t nx = (size_t)Msz * Ksz;   // 33,554,432
  const size_t nwq = (size_t)Nsz * Ksz;  // 45,088,768
  const size_t need = nx + nwq + Msz * sizeof(float);

  if (ws_size >= need) {
    signed char* xq = (signed char*)d_ws;
    signed char* wp = xq + nx;
    float* qsd = (float*)(wp + nwq);
    quant_x<<<dim3(Msz), dim3(256), 0, stream>>>(x, xq, qsd);
    pack_w<<<dim3((unsigned)(nwq / (16 * 256))), dim3(256), 0, stream>>>(
        (const int4*)Wq, (unsigned*)wp);
    gemm_i8<<<dim3(NWG), dim3(512), 0, stream>>>(xq, wp, qsd, scale, bias, out);
  } else {
    dim3 grid(Nsz / BN, Msz / BM);
    gemm_bf16_inline<<<grid, dim3(256), 0, stream>>>(x, Wq, scale, bias, out);
  }
}

// Round 4
// 1008.561 us; speedup vs baseline: 1.1530x; 1.0744x over previous
//
#include <hip/hip_runtime.h>
#include <cstdint>
#include <cstddef>

// Int8Linear + exact GELU on MI355X — int8 MFMA, 256x256, 8 phases/2 tiles,
// cross-phase register prefetch, 1 barrier/phase, zero-VALU inner loop.
// y[m][n] = gelu( scale[n] * sum_k x[m][k]*Wq[n][k] + b[n] )
// M=8192, N=11008, K=4096.
//
// Round 6 theory: rounds 0-5 all ~700us because the phase is SERIAL:
// VALU addr-calc (~550cy) -> barrier -> LDS drain (~576cy) -> MFMA (653cy)
// -> barrier, at 2 waves/SIMD lockstep. vmcnt waits were provably slack in
// round 5 (targets >=12k cyc old) yet phase stayed 2383cy => not a memory-
// wait problem. Fix: (a) ds_reads for phase p+1 issued BEFORE MFMA(p),
// consumed via lgkmcnt(4) a phase later -> LDS drain overlaps MFMA pipe;
// (b) one barrier per phase; (c) all addresses hoisted: ds_read = 4 lane
// base regs + imm (swizzle term lane-const: row&7==lane&7), staging =
// per-thread voffset + uniform SGPR (kt*128 + q*131072).
// Ledger: stage->read gap >=5 phases; uniform vmcnt(8)/phase; lgkm(4|12).

#define Msz 8192
#define Nsz 11008
#define Ksz 4096

#define TM 256
#define TN 256
#define TK 128            // K-bytes (= K-elems, i8) per tile row
#define NT (Ksz / TK)     // 32 K-tiles
#define NI (NT / 2)       // 16 iterations (2 tiles per iteration)
#define NWG ((Msz / TM) * (Nsz / TN))  // 1376, % 8 == 0
#define CPX (NWG / 8)

#define BM 128
#define BN 128

typedef __attribute__((ext_vector_type(4))) int int4v;
typedef __attribute__((ext_vector_type(8))) short short8;
typedef __attribute__((ext_vector_type(4))) float floatx4;

__device__ __forceinline__ void async16(const void* g, void* l) {
  __builtin_amdgcn_global_load_lds(
      (const __attribute__((address_space(1))) void*)g,
      (__attribute__((address_space(3))) void*)l, 16, 0, 0);
}

// ---- fused pre-pass: quant_x rows [0,8192) + pack_w chunks [8192,19200) ---
__global__ __launch_bounds__(256) void prep(
    const float* __restrict__ x, const int4* __restrict__ w,
    signed char* __restrict__ xq, unsigned* __restrict__ wp,
    float* __restrict__ qs) {
  const int tid = threadIdx.x;
  if (blockIdx.x < 8192) {
    const int row = blockIdx.x;
    const int lane = tid & 63;
    const int wave = tid >> 6;
    const float4* xr = (const float4*)(x + (size_t)row * Ksz);
    float4 v[4];
    float m = 0.f;
#pragma unroll
    for (int t = 0; t < 4; ++t) {
      v[t] = xr[tid + t * 256];
      m = fmaxf(m, fmaxf(fmaxf(fabsf(v[t].x), fabsf(v[t].y)),
                         fmaxf(fabsf(v[t].z), fabsf(v[t].w))));
    }
#pragma unroll
    for (int o = 32; o > 0; o >>= 1) m = fmaxf(m, __shfl_down(m, o));
    __shared__ float sm[4];
    if (lane == 0) sm[wave] = m;
    __syncthreads();
    const float am = fmaxf(fmaxf(sm[0], sm[1]), fmaxf(sm[2], sm[3]));
    const float rs = am > 0.f ? 127.0f / am : 0.f;
    if (tid == 0) qs[row] = am * (1.0f / 127.0f);
    unsigned* outd = (unsigned*)(xq + (size_t)row * Ksz);
#pragma unroll
    for (int t = 0; t < 4; ++t) {
      int q0 = __float2int_rn(fminf(fmaxf(v[t].x * rs, -127.f), 127.f));
      int q1 = __float2int_rn(fminf(fmaxf(v[t].y * rs, -127.f), 127.f));
      int q2 = __float2int_rn(fminf(fmaxf(v[t].z * rs, -127.f), 127.f));
      int q3 = __float2int_rn(fminf(fmaxf(v[t].w * rs, -127.f), 127.f));
      outd[tid + t * 256] = (unsigned)(q0 & 255) | ((unsigned)(q1 & 255) << 8) |
                            ((unsigned)(q2 & 255) << 16) | ((unsigned)q3 << 24);
    }
  } else {
    const unsigned gid = (blockIdx.x - 8192) * 256 + tid;
    const unsigned stride = 11008u * 256u;
#pragma unroll
    for (int t = 0; t < 4; ++t) {
      const unsigned idx = gid + t * stride;
      const int4 a = w[idx];
      wp[idx] = (unsigned)(a.x & 255) | ((unsigned)(a.y & 255) << 8) |
                ((unsigned)(a.z & 255) << 16) | ((unsigned)a.w << 24);
    }
  }
}

// ---- main GEMM -----------------------------------------------------------
// LDS map (131072 B): sA0 @0, sA1 @32768, sB0 @65536, sB1 @98304.
// Layouts: A buf: row r (0..255: half*128 + q*32 + s), 128 B/row; byte =
// half*16384 + q*4096 + s*128 + col. B buf: row (hh*128 + rho*64 + t>>3),
// byte = hh*16384 + rho*8192 + (t>>3)*128 + col. Swizzle: LDS[r][c] holds
// global k-slot c ^ ((r&7)<<4), applied on the GLOBAL source (dest linear).

#define RD_A(DST, BUF, Q)                                                      \
  DST[0] = *(const int4v*)(ldsb + aRd0 + ((BUF)*32768 + (2*(Q)+0)*2048));      \
  DST[1] = *(const int4v*)(ldsb + aRd1 + ((BUF)*32768 + (2*(Q)+0)*2048));      \
  DST[2] = *(const int4v*)(ldsb + aRd0 + ((BUF)*32768 + (2*(Q)+1)*2048));      \
  DST[3] = *(const int4v*)(ldsb + aRd1 + ((BUF)*32768 + (2*(Q)+1)*2048));

#define RD_B(DST, BUF)                                                         \
  _Pragma("unroll") for (int jj = 0; jj < 4; ++jj) {                           \
    DST[jj*2+0] = *(const int4v*)(ldsb + bRd0 + ((BUF)*32768 + jj*2048));      \
    DST[jj*2+1] = *(const int4v*)(ldsb + bRd1 + ((BUF)*32768 + jj*2048));      \
  }

#define MM(Q, A, B)                                                            \
  __builtin_amdgcn_s_setprio(1);                                               \
  _Pragma("unroll") for (int kk = 0; kk < 2; ++kk)                             \
  _Pragma("unroll") for (int ii = 0; ii < 2; ++ii)                             \
  _Pragma("unroll") for (int jj = 0; jj < 4; ++jj)                             \
    acc[2*(Q)+ii][jj] = __builtin_amdgcn_mfma_i32_16x16x64_i8(                 \
        A[ii*2+kk], B[jj*2+kk], acc[2*(Q)+ii][jj], 0, 0, 0);                   \
  __builtin_amdgcn_s_setprio(0);

#define ST_A(BUF, Q, KT)                                                       \
  async16(aG + (size_t)(KT)*128 + (size_t)(Q)*131072,                          \
          ldsb + aStD + ((BUF)*32768 + (Q)*4096));

#define ST_B(BUF, HH, KT)                                                      \
  async16(bG + (size_t)(HH)*524288 + (size_t)(KT)*128,                         \
          ldsb + bStD + (65536 + (BUF)*32768 + (HH)*16384));                   \
  async16(bG2 + (size_t)(HH)*524288 + (size_t)(KT)*128,                        \
          ldsb + bStD + (65536 + (BUF)*32768 + (HH)*16384 + 8192));

#define SB __builtin_amdgcn_sched_barrier(0)
#define VMW(N) asm volatile("s_waitcnt vmcnt(" #N ")" ::: "memory")
#define LGW(N) asm volatile("s_waitcnt lgkmcnt(" #N ")" ::: "memory")

// Phase: {ds_read next-phase frags || issue stages} -> lgkm(prev reads) ->
// MFMA(this phase, prefetched frags) -> vmcnt(8) -> barrier.
#define PH(RD_CODE, STAGE_CODE, LGN, Q, ASET, BSET)                            \
  {                                                                            \
    RD_CODE;                                                                   \
    STAGE_CODE;                                                                \
    LGW(LGN);                                                                  \
    SB;                                                                        \
    MM(Q, ASET, BSET);                                                         \
    SB;                                                                        \
    VMW(8);                                                                    \
    __builtin_amdgcn_s_barrier();                                              \
    SB;                                                                        \
  }

__global__ __launch_bounds__(512, 2) void gemm_i8(
    const signed char* __restrict__ A8,  // [M][K] int8
    const signed char* __restrict__ B8,  // [N][K] int8
    const float* __restrict__ qs,        // [M] per-row x scales
    const float* __restrict__ scale, const float* __restrict__ bias,
    float* __restrict__ out) {
  __shared__ signed char ldsb[131072];

  const int tid = threadIdx.x;
  const int wave = tid >> 6;
  const int lane = tid & 63;
  const int wr = wave >> 2;  // 0..1 -> M-half of tile
  const int wc = wave & 3;   // 0..3 -> N-quarter

  const int bid = blockIdx.x;
  const int swz = (bid & 7) * CPX + (bid >> 3);
  const int bm0 = (swz & 31) * TM;
  const int bn0 = (swz >> 5) * TN;

  // ---- hoisted ds_read bases (per-lane constants; row&7 == lane&7) ----
  const int lane15 = lane & 15, lane7 = lane & 7, lg = lane >> 4;
  const int kkp0 = ((0 * 4 + lg) ^ lane7) << 4;
  const int kkp1 = ((1 * 4 + lg) ^ lane7) << 4;
  const int aRd0 = wr * 16384 + lane15 * 128 + kkp0;
  const int aRd1 = wr * 16384 + lane15 * 128 + kkp1;
  const int bRd0 = 65536 + wc * 8192 + lane15 * 128 + kkp0;
  const int bRd1 = 65536 + wc * 8192 + lane15 * 128 + kkp1;

  // ---- hoisted staging addresses ----
  // A: row = half*128 + q*32 + s; s = (tid&255)>>3; col-swz uses s&7.
  const int sA_ = (tid & 255) >> 3;
  const signed char* aG =
      A8 + (size_t)(bm0 + (tid >> 8) * 128 + sA_) * Ksz +
      (((tid & 7) ^ (sA_ & 7)) << 4);
  const int aStD = (tid >> 8) * 16384 + (tid & 255) * 16;
  // B: rho=0 row = t>>3; rho=1 row = 64 + t>>3; swz uses (t>>3)&7 both.
  const int sB_ = tid >> 3;
  const signed char* bG =
      B8 + (size_t)(bn0 + sB_) * Ksz + (((tid & 7) ^ (sB_ & 7)) << 4);
  const signed char* bG2 =
      B8 + (size_t)(bn0 + 64 + sB_) * Ksz + (((tid & 7) ^ (sB_ & 7)) << 4);
  const int bStD = tid * 16;

  int4v acc[8][4];
#pragma unroll
  for (int i = 0; i < 8; ++i)
#pragma unroll
    for (int j = 0; j < 4; ++j) acc[i][j] = (int4v)0;
  int4v afA[4], afB[4], bfA[8], bfB[8];

  // ---- prologue: 15 stage units mimicking steady state ----
  ST_A(0, 0, 0) ST_B(0, 0, 0)
  ST_A(0, 1, 0) ST_B(0, 1, 0)
  ST_A(0, 2, 0)
  ST_A(0, 3, 0)
  ST_A(1, 0, 1) ST_B(1, 0, 1)
  ST_A(1, 1, 1) ST_B(1, 1, 1)
  ST_A(1, 2, 1)
  VMW(7);  // completes A(0) all slices + B(0) both halves
  __builtin_amdgcn_s_barrier();
  SB;
  RD_A(afA, 0, 0)  // frags for P1 (A(0)s0)
  RD_B(bfA, 0)     // B(0)

  for (int j = 0; j < NI; ++j) {
    const int t1 = 2 * j + 1;
    const int t2 = (2 * j + 2 < NT) ? 2 * j + 2 : NT - 1;
    const int t3 = (2 * j + 3 < NT) ? 2 * j + 3 : NT - 1;
    // P1..P8; reads are for NEXT phase, MFMA uses prev-phase frags.
    PH(RD_A(afB, 0, 1), ST_A(1, 3, t1), 4, 0, afA, bfA)
    PH(RD_A(afA, 0, 2), ST_A(0, 0, t2) ST_B(0, 0, t2), 4, 1, afB, bfA)
    PH(RD_A(afB, 0, 3), ST_A(0, 1, t2) ST_B(0, 1, t2), 4, 2, afA, bfA)
    PH(RD_A(afA, 1, 0) RD_B(bfB, 1), ST_A(0, 2, t2), 12, 3, afB, bfA)
    PH(RD_A(afB, 1, 1), ST_A(0, 3, t2), 4, 0, afA, bfB)
    PH(RD_A(afA, 1, 2), ST_A(1, 0, t3) ST_B(1, 0, t3), 4, 1, afB, bfB)
    PH(RD_A(afB, 1, 3), ST_A(1, 1, t3) ST_B(1, 1, t3), 4, 2, afA, bfB)
    PH(RD_A(afA, 0, 0) RD_B(bfA, 0), ST_A(1, 2, t3), 12, 3, afB, bfB)
  }
  asm volatile("s_waitcnt vmcnt(0) lgkmcnt(0)" ::: "memory");

  // ---- epilogue: col = lane&15 (N), row = (lane>>4)*4 + reg (M) ----
  float sc[4], bb[4];
#pragma unroll
  for (int jj = 0; jj < 4; ++jj) {
    const int col = bn0 + wc * 64 + jj * 16 + lane15;
    sc[jj] = scale[col];
    bb[jj] = bias[col];
  }
#pragma unroll
  for (int i = 0; i < 8; ++i) {
    const int row0 = bm0 + wr * 128 + i * 16 + lg * 4;
    float qv[4];
#pragma unroll
    for (int r = 0; r < 4; ++r) qv[r] = qs[row0 + r];
#pragma unroll
    for (int jj = 0; jj < 4; ++jj) {
      const int col = bn0 + wc * 64 + jj * 16 + lane15;
#pragma unroll
      for (int r = 0; r < 4; ++r) {
        float v = (float)acc[i][jj][r] * (qv[r] * sc[jj]) + bb[jj];
        v = 0.5f * v * (1.0f + erff(v * 0.7071067811865476f));
        out[(size_t)(row0 + r) * Nsz + col] = v;
      }
    }
  }
}

// ---- fallback bf16 GEMM (inline conversion) if ws is too small ------------
__device__ __forceinline__ unsigned int f2bf(float f) {
  unsigned int u = __builtin_bit_cast(unsigned int, f);
  unsigned int r = u + 0x7FFFu + ((u >> 16) & 1u);
  return r >> 16;
}

__global__ __launch_bounds__(256) void gemm_bf16_inline(
    const float* __restrict__ Af, const int* __restrict__ Bi,
    const float* __restrict__ scale, const float* __restrict__ bias,
    float* __restrict__ out) {
  __shared__ unsigned short sA[BM * 32];
  __shared__ unsigned short sB[BN * 32];
  const int tid = threadIdx.x;
  const int wave = tid >> 6;
  const int lane = tid & 63;
  const int bn0 = blockIdx.x * BN;
  const int bm0 = blockIdx.y * BM;
  const int mw = (wave >> 1) * 64;
  const int nw = (wave & 1) * 64;
  floatx4 acc[4][4];
#pragma unroll
  for (int i = 0; i < 4; ++i)
#pragma unroll
    for (int j = 0; j < 4; ++j) acc[i][j] = (floatx4)0.f;
  for (int k0 = 0; k0 < Ksz; k0 += 32) {
#pragma unroll
    for (int it = 0; it < 4; ++it) {
      const int f = tid + it * 256;
      const int row = f >> 3;
      const int c4 = (f & 7) * 4;
      const float4 v = *(const float4*)(Af + (size_t)(bm0 + row) * Ksz + k0 + c4);
      uint2 p;
      p.x = f2bf(v.x) | (f2bf(v.y) << 16);
      p.y = f2bf(v.z) | (f2bf(v.w) << 16);
      *(uint2*)&sA[row * 32 + c4] = p;
      const int4 w2 = *(const int4*)(Bi + (size_t)(bn0 + row) * Ksz + k0 + c4);
      uint2 q;
      q.x = f2bf((float)w2.x) | (f2bf((float)w2.y) << 16);
      q.y = f2bf((float)w2.z) | (f2bf((float)w2.w) << 16);
      *(uint2*)&sB[row * 32 + c4] = q;
    }
    __syncthreads();
    short8 af[4], bfr[4];
    const int kof2 = (lane >> 4) * 8;
#pragma unroll
    for (int i = 0; i < 4; ++i) {
      af[i] = *(const short8*)&sA[(mw + i * 16 + (lane & 15)) * 32 + kof2];
      bfr[i] = *(const short8*)&sB[(nw + i * 16 + (lane & 15)) * 32 + kof2];
    }
#pragma unroll
    for (int i = 0; i < 4; ++i)
#pragma unroll
      for (int j = 0; j < 4; ++j)
        acc[i][j] =
            __builtin_amdgcn_mfma_f32_16x16x32_bf16(af[i], bfr[j], acc[i][j], 0, 0, 0);
    __syncthreads();
  }
#pragma unroll
  for (int j = 0; j < 4; ++j) {
    const int col = bn0 + nw + j * 16 + (lane & 15);
    const float s = scale[col];
    const float bb = bias[col];
#pragma unroll
    for (int i = 0; i < 4; ++i) {
      const int row0 = bm0 + mw + i * 16 + (lane >> 4) * 4;
#pragma unroll
      for (int r = 0; r < 4; ++r) {
        float v = acc[i][j][r] * s + bb;
        v = 0.5f * v * (1.0f + erff(v * 0.7071067811865476f));
        out[(size_t)(row0 + r) * Nsz + col] = v;
      }
    }
  }
}

extern "C" void kernel_launch(void* const* d_in, const int* in_sizes, int n_in,
                              void* d_out, int out_size, void* d_ws, size_t ws_size,
                              hipStream_t stream) {
  const float* x = (const float*)d_in[0];      // [M][K] fp32
  const int* Wq = (const int*)d_in[1];         // [N][K] int32 (int8 values)
  const float* scale = (const float*)d_in[2];  // [N]
  const float* bias = (const float*)d_in[3];   // [N]
  float* out = (float*)d_out;                  // [M][N] fp32

  const size_t nx = (size_t)Msz * Ksz;   // 33,554,432
  const size_t nwq = (size_t)Nsz * Ksz;  // 45,088,768
  const size_t need = nx + nwq + Msz * sizeof(float);

  if (ws_size >= need) {
    signed char* xq = (signed char*)d_ws;
    signed char* wp = xq + nx;
    float* qsd = (float*)(wp + nwq);
    prep<<<dim3(8192 + 11008), dim3(256), 0, stream>>>(
        x, (const int4*)Wq, xq, (unsigned*)wp, qsd);
    gemm_i8<<<dim3(NWG), dim3(512), 0, stream>>>(xq, wp, qsd, scale, bias, out);
  } else {
    dim3 grid(Nsz / BN, Msz / BM);
    gemm_bf16_inline<<<grid, dim3(256), 0, stream>>>(x, Wq, scale, bias, out);
  }
}